// Round 10
// baseline (246.671 us; speedup 1.0000x reference)
//
#include <hip/hip_runtime.h>

// Parametric LIF forward (spike output only).
// x: [B=64, T=64, N=8192] fp32.  out: same shape, values in {0,1}.
// Recurrence per (b,n):  u = last*sig + x[t];  s = (u >= th);
//                        last = (u + lamb*(u-last)) * (1-s)
//
// History:
//  R3-R7 fused variants: ALL ~76-81us regardless of structure.
//  R9 diagnostic: compute C~=26.6us (128MiB strided READ ~5 TB/s: fine);
//    expand E~=55-60us (128MiB linear WRITE ~2.3 TB/s: broken).
//  R10: fused with PLAIN stores = 81.2us = NT. Store flavor irrelevant;
//    WRITE_SIZE exactly 128MiB (perfect line combining) -> only RATE is bad.
//  Surviving theory: WRITE-RUN LENGTH. Fast writers (rocclr fills, 6.7 TB/s)
//  give each wave a long sequential store run. Our slow writers emit 0.5-1KiB
//  islands from thousands of waves interleaved -> HBM write queues see
//  fragmented bursts, poor row locality (~2.4 TB/s). Reads survive this
//  (deep reorder); writes don't. Alternative (distinguished by this round):
//  d_out write-rate cap -> null result.
// R11: split kept; compute unchanged (proven). Expand-v2 mimics the fill:
//  4096 waves (1024 blocks x 4), each owns ONE contiguous 32 KiB out run =
//  32 x dwordx4 plain stores; all 32 spk u32 loads batched into registers
//  up-front (loads never interleave the store burst).
//  absmax 0: expand is a pure re-encoding of spk bytes; spike arithmetic
//  identical to the R2-verified kernel.

#define LIF_B 64
#define LIF_T 64
#define LIF_N 8192
#define NV2 (LIF_N / 2)            // f2 per row = 4096
#define UN 8                       // t-steps per stage
#define NSTAGE (LIF_T / UN)        // 8
#define WS_BYTES ((size_t)LIF_B * LIF_T * LIF_N)   // 32 MiB u8 spikes

typedef float f2 __attribute__((ext_vector_type(2)));
typedef float f4 __attribute__((ext_vector_type(4)));
typedef unsigned char u8;
typedef unsigned int  u32;
typedef u8 uc2 __attribute__((ext_vector_type(2)));

// ---------------- Kernel 1: recurrence, u8 spike emit (PROVEN ~26.6us) ---
__global__ __launch_bounds__(256) void lif_compute_kernel(
    const f2* __restrict__ x,
    const float* __restrict__ tau_p,
    const float* __restrict__ lamb_p,
    const float* __restrict__ th_p,
    uc2* __restrict__ spk)           // same linear indexing as f2 view of out
{
    const int tid = blockIdx.x * blockDim.x + threadIdx.x;   // 0 .. B*NV2-1
    const int b   = tid >> 12;                               // / NV2
    const int n2  = tid & (NV2 - 1);

    const float sig  = 1.0f / (1.0f + expf(-tau_p[0]));      // 0.5 exact
    const float lamb = lamb_p[0];
    const float th   = th_p[0];

    float lx = 0.0f, ly = 0.0f;
    const size_t base = (size_t)b * LIF_T * NV2 + n2;

    f2 cur[UN], nxt[UN];

#pragma unroll
    for (int i = 0; i < UN; ++i)
        cur[i] = x[base + (size_t)i * NV2];

#pragma unroll
    for (int k = 0; k < NSTAGE; ++k) {
        if (k + 1 < NSTAGE) {
#pragma unroll
            for (int i = 0; i < UN; ++i)
                nxt[i] = x[base + (size_t)((k + 1) * UN + i) * NV2];
        }

#pragma unroll
        for (int i = 0; i < UN; ++i) {
            f2 v = cur[i];
            uc2 sb;
            {
                float u = __fadd_rn(__fmul_rn(lx, sig), v.x);
                bool  c = (u >= th);
                float s = c ? 1.0f : 0.0f;
                lx = __fmul_rn(__fadd_rn(u, __fmul_rn(lamb, __fsub_rn(u, lx))),
                               __fsub_rn(1.0f, s));
                sb.x = c ? (u8)1 : (u8)0;
            }
            {
                float u = __fadd_rn(__fmul_rn(ly, sig), v.y);
                bool  c = (u >= th);
                float s = c ? 1.0f : 0.0f;
                ly = __fmul_rn(__fadd_rn(u, __fmul_rn(lamb, __fsub_rn(u, ly))),
                               __fsub_rn(1.0f, s));
                sb.y = c ? (u8)1 : (u8)0;
            }
            // Plain cached store: 2B/lane, L2-resident.
            spk[base + (size_t)(k * UN + i) * NV2] = sb;
        }

#pragma unroll
        for (int i = 0; i < UN; ++i)
            cur[i] = nxt[i];
    }
}

// ---------------- Kernel 2 v2: long-run expander -------------------------
// 4096 waves; each wave owns one contiguous 32 KiB out run (2048 f4).
// Per lane: 32 u32 loads (registers first), then 32 dwordx4 plain stores.
__global__ __launch_bounds__(256) void lif_expand_kernel(
    const u32* __restrict__ spk,
    f4* __restrict__ out)
{
    const int wave = blockIdx.x * 4 + (threadIdx.x >> 6);    // 0..4095
    const int lane = threadIdx.x & 63;
    const size_t base = (size_t)wave * 2048 + lane;          // f4 == u32 index

    u32 w[32];
#pragma unroll
    for (int i = 0; i < 32; ++i)
        w[i] = spk[base + i * 64];

#pragma unroll
    for (int i = 0; i < 32; ++i) {
        const u32 v = w[i];
        f4 o;
        o.x = (v & 0x000000ffu) ? 1.0f : 0.0f;
        o.y = (v & 0x0000ff00u) ? 1.0f : 0.0f;
        o.z = (v & 0x00ff0000u) ? 1.0f : 0.0f;
        o.w = (v & 0xff000000u) ? 1.0f : 0.0f;
        out[base + i * 64] = o;                              // plain store
    }
}

// ---------------- Fallback: proven fused kernel (R2 shape) ---------------
__global__ __launch_bounds__(256, 4) void lif_fused_kernel(
    const f2* __restrict__ x,
    const float* __restrict__ tau_p,
    const float* __restrict__ lamb_p,
    const float* __restrict__ th_p,
    f2* __restrict__ out)
{
    const int tid = blockIdx.x * blockDim.x + threadIdx.x;
    const int b   = tid >> 12;
    const int n2  = tid & (NV2 - 1);

    const float sig  = 1.0f / (1.0f + expf(-tau_p[0]));
    const float lamb = lamb_p[0];
    const float th   = th_p[0];

    float lx = 0.0f, ly = 0.0f;
    const size_t base = (size_t)b * LIF_T * NV2 + n2;

    f2 cur[UN], nxt[UN];
#pragma unroll
    for (int i = 0; i < UN; ++i)
        cur[i] = x[base + (size_t)i * NV2];

#pragma unroll
    for (int k = 0; k < NSTAGE; ++k) {
        if (k + 1 < NSTAGE) {
#pragma unroll
            for (int i = 0; i < UN; ++i)
                nxt[i] = x[base + (size_t)((k + 1) * UN + i) * NV2];
        }
#pragma unroll
        for (int i = 0; i < UN; ++i) {
            f2 v = cur[i];
            f2 sv;
            {
                float u = __fadd_rn(__fmul_rn(lx, sig), v.x);
                float s = (u >= th) ? 1.0f : 0.0f;
                lx = __fmul_rn(__fadd_rn(u, __fmul_rn(lamb, __fsub_rn(u, lx))),
                               __fsub_rn(1.0f, s));
                sv.x = s;
            }
            {
                float u = __fadd_rn(__fmul_rn(ly, sig), v.y);
                float s = (u >= th) ? 1.0f : 0.0f;
                ly = __fmul_rn(__fadd_rn(u, __fmul_rn(lamb, __fsub_rn(u, ly))),
                               __fsub_rn(1.0f, s));
                sv.y = s;
            }
            out[base + (size_t)(k * UN + i) * NV2] = sv;
        }
#pragma unroll
        for (int i = 0; i < UN; ++i)
            cur[i] = nxt[i];
    }
}

extern "C" void kernel_launch(void* const* d_in, const int* in_sizes, int n_in,
                              void* d_out, int out_size, void* d_ws, size_t ws_size,
                              hipStream_t stream) {
    (void)in_sizes; (void)n_in; (void)out_size;

    const f2*    x     = (const f2*)d_in[0];
    const float* tau_p = (const float*)d_in[1];
    const float* lamb  = (const float*)d_in[2];
    const float* th    = (const float*)d_in[3];

    if (d_ws != nullptr && ws_size >= WS_BYTES) {
        lif_compute_kernel<<<1024, 256, 0, stream>>>(x, tau_p, lamb, th, (uc2*)d_ws);
        lif_expand_kernel<<<1024, 256, 0, stream>>>((const u32*)d_ws, (f4*)d_out);
    } else {
        lif_fused_kernel<<<1024, 256, 0, stream>>>(x, tau_p, lamb, th, (f2*)d_out);
    }
}